// Round 2
// baseline (423.982 us; speedup 1.0000x reference)
//
#include <hip/hip_runtime.h>
#include <stdint.h>

#define NPIX 65536
#define IGN (-255)

// ---------------- threefry2x32 (exact JAX implementation) ----------------
__device__ __forceinline__ uint32_t rotl32(uint32_t v, uint32_t r){ return (v<<r)|(v>>(32u-r)); }

__device__ __forceinline__ void tf2x32(uint32_t k0, uint32_t k1, uint32_t x0, uint32_t x1,
                                       uint32_t &o0, uint32_t &o1){
  uint32_t k2 = k0 ^ k1 ^ 0x1BD11BDAu;
  x0 += k0; x1 += k1;
#define TFR(r) { x0 += x1; x1 = rotl32(x1,(r)); x1 ^= x0; }
  TFR(13u) TFR(15u) TFR(26u) TFR(6u)   x0 += k1; x1 += k2 + 1u;
  TFR(17u) TFR(29u) TFR(16u) TFR(24u)  x0 += k2; x1 += k0 + 2u;
  TFR(13u) TFR(15u) TFR(26u) TFR(6u)   x0 += k0; x1 += k1 + 3u;
  TFR(17u) TFR(29u) TFR(16u) TFR(24u)  x0 += k1; x1 += k2 + 4u;
  TFR(13u) TFR(15u) TFR(26u) TFR(6u)   x0 += k2; x1 += k0 + 5u;
#undef TFR
  o0 = x0; o1 = x1;
}

// pack score+index so that u64 max == (higher score, then lower index)
__device__ __forceinline__ uint64_t packCand(uint32_t bits, uint32_t pix){
  float f = __uint_as_float((bits >> 9) | 0x3f800000u) - 1.0f;  // jax uniform [0,1)
  uint32_t u = __float_as_uint(f) ^ 0x80000000u;                // monotone map (f>=0)
  return ((uint64_t)u << 32) | (uint64_t)(0xFFFFFFFFu - pix);
}

// sorted-descending 10-element list, sentinel 0
__device__ __forceinline__ void t10_insert(uint64_t* l, uint64_t c){
  if (c > l[9]) {
    l[9] = c;
#pragma unroll
    for (int i = 9; i > 0; --i){
      uint64_t a = l[i-1], b2 = l[i];
      if (b2 > a){ l[i-1] = b2; l[i] = a; }
    }
  }
}

__global__ __launch_bounds__(256)
void apm_kernel(const float* __restrict__ x, int* __restrict__ out){
  const int b = blockIdx.x;
  const int tid = threadIdx.x;
  const float* img = x + (size_t)b * NPIX;
  int* outb = out + (size_t)b * NPIX;

  __shared__ uint32_t hist[256];
  __shared__ float csum[256], cvsum[256];
  __shared__ uint64_t cand[2560];     // 256 threads x 10
  __shared__ uint64_t merged[160];    // 16 x 10
  __shared__ uint32_t s_kw[4];
  __shared__ float s_lit;
  __shared__ int s_fgr[10], s_fgc[10], s_bgr[10], s_bgc[10];
  __shared__ int s_nfg, s_nbg;

  hist[tid] = 0u;

  // ---- fill output with IGNORE (coalesced int4) ----
  {
    int4 f4 = make_int4(IGN, IGN, IGN, IGN);
    int4* o4 = (int4*)outb;
#pragma unroll
    for (int j = 0; j < 64; ++j) o4[j*256 + tid] = f4;
  }

  // ---- derive fg/bg keys: PARTITIONABLE (foldlike) split semantics ----
  // split(key(1),(256,2)): key #m = threefry((0,1), x0=hi64(m)=0, x1=m), stacked (o0,o1)
  if (tid < 2){
    uint32_t o0, o1;
    tf2x32(0u, 1u, 0u, (uint32_t)(2*b + tid), o0, o1);
    s_kw[2*tid]   = o0;
    s_kw[2*tid+1] = o1;
  }
  __syncthreads();

  // ---- histogram of u8 = clip(floor(x*255),0,255) ----
  for (int j = 0; j < 64; ++j){
    float4 v = ((const float4*)img)[j*256 + tid];
    int u0 = min(max((int)floorf(v.x*255.0f),0),255);
    int u1 = min(max((int)floorf(v.y*255.0f),0),255);
    int u2 = min(max((int)floorf(v.z*255.0f),0),255);
    int u3 = min(max((int)floorf(v.w*255.0f),0),255);
    atomicAdd(&hist[u0],1u); atomicAdd(&hist[u1],1u);
    atomicAdd(&hist[u2],1u); atomicAdd(&hist[u3],1u);
  }
  __syncthreads();

  // ---- Otsu + Li (serial per image; parallel across 256 blocks) ----
  if (tid == 0){
    int imin = 255;
    for (int i = 0; i < 256; ++i){ if (hist[i]){ imin = i; break; } }
    float img_min = (float)imin;
    float s_tot_o = 0.0f;
    for (int i = 0; i < 256; ++i) s_tot_o += (float)hist[i]*(float)i;  // exact ints < 2^24
    const float total = 65536.0f;
    float cw = 0.0f, cs = 0.0f, csh = 0.0f, best = -1.0f; int bestIdx = 0;
    for (int i = 0; i < 256; ++i){
      float h = (float)hist[i];
      cw += h; cs += h*(float)i; csh += h*((float)i - img_min);  // all exact ints
      csum[i] = cw; cvsum[i] = csh;
      if (i < 255){
        float w0 = cw, w1 = total - cw;
        float m0 = cs / fmaxf(w0, 1e-12f);
        float m1 = (s_tot_o - cs) / fmaxf(w1, 1e-12f);
        float d = m0 - m1;
        float vb = (w0*w1) * (d*d);
        if (vb > best){ best = vb; bestIdx = i; }   // argmax: first max
      }
    }
    float otsu = fminf(fmaxf((float)bestIdx, 1.0f), 254.0f);
    float n_tot = csum[255], s_tot = cvsum[255];
    float t_curr = otsu - img_min, t_prev = t_curr + 10.0f;
    int it = 0;
    while (fabsf(t_curr - t_prev) > 0.5f && it < 64){
      int idx = min(max((int)floorf(t_curr + img_min), 0), 255);
      float n_back = csum[idx], s_back = cvsum[idx];
      float n_fore = n_tot - n_back, s_fore = s_tot - s_back;
      float mean_back = (n_back > 0.0f) ? (s_back / fmaxf(n_back, 1.0f)) : 0.0f;
      float mean_fore = s_fore / fmaxf(n_fore, 1.0f);
      float t_next = (mean_back - mean_fore) /
                     (logf(fmaxf(mean_back, 1e-12f)) - logf(fmaxf(mean_fore, 1e-12f)));
      if (mean_back < 1e-12f) t_next = mean_fore * 0.5f;
      t_prev = t_curr; t_curr = t_next; ++it;
    }
    s_lit = t_curr + img_min;
  }
  __syncthreads();

  // ---- threefry scoring + per-thread top-10 ----
  // PARTITIONABLE uniform bits: pixel i -> threefry(key, 0, i); bits = o0 ^ o1
  const float lit = s_lit;
  const uint32_t fk0 = s_kw[0], fk1 = s_kw[1], bk0 = s_kw[2], bk1 = s_kw[3];
  uint64_t lfg[10], lbg[10];
#pragma unroll
  for (int i = 0; i < 10; ++i){ lfg[i] = 0ull; lbg[i] = 0ull; }

  for (int j = 0; j < 64; ++j){
    int p4 = j*256 + tid;
    float4 v = ((const float4*)img)[p4];
    uint32_t pix0 = (uint32_t)(p4*4);
    float vv[4] = {v.x, v.y, v.z, v.w};
#pragma unroll
    for (int s = 0; s < 4; ++s){
      uint32_t pix = pix0 + (uint32_t)s;
      int q = min(max((int)floorf(vv[s]*255.0f),0),255);
      bool r = ((float)q > lit);
      uint32_t kk0 = r ? fk0 : bk0;
      uint32_t kk1 = r ? fk1 : bk1;
      uint32_t o0,o1;
      tf2x32(kk0, kk1, 0u, pix, o0, o1);
      uint64_t c = packCand(o0 ^ o1, pix);
      if (r) t10_insert(lfg, c); else t10_insert(lbg, c);
    }
  }

  // ---- merge 256 lists -> 16 -> 1, extract points ----
  // fg
  {
#pragma unroll
    for (int i = 0; i < 10; ++i) cand[tid*10 + i] = lfg[i];
    __syncthreads();
    if (tid < 16){
      uint64_t t[10];
#pragma unroll
      for (int i = 0; i < 10; ++i) t[i] = 0ull;
      for (int i = 0; i < 160; ++i) t10_insert(t, cand[tid*160 + i]);
#pragma unroll
      for (int i = 0; i < 10; ++i) merged[tid*10 + i] = t[i];
    }
    __syncthreads();
    if (tid == 0){
      uint64_t t[10];
#pragma unroll
      for (int i = 0; i < 10; ++i) t[i] = 0ull;
      for (int i = 0; i < 160; ++i) t10_insert(t, merged[i]);
      int n = 0;
      for (int i = 0; i < 10; ++i){
        if (t[i]){
          uint32_t pix = 0xFFFFFFFFu - (uint32_t)(t[i] & 0xFFFFFFFFull);
          s_fgr[n] = (int)(pix >> 8); s_fgc[n] = (int)(pix & 255u); ++n;
        }
      }
      s_nfg = n;
    }
    __syncthreads();
  }
  // bg
  {
#pragma unroll
    for (int i = 0; i < 10; ++i) cand[tid*10 + i] = lbg[i];
    __syncthreads();
    if (tid < 16){
      uint64_t t[10];
#pragma unroll
      for (int i = 0; i < 10; ++i) t[i] = 0ull;
      for (int i = 0; i < 160; ++i) t10_insert(t, cand[tid*160 + i]);
#pragma unroll
      for (int i = 0; i < 10; ++i) merged[tid*10 + i] = t[i];
    }
    __syncthreads();
    if (tid == 0){
      uint64_t t[10];
#pragma unroll
      for (int i = 0; i < 10; ++i) t[i] = 0ull;
      for (int i = 0; i < 160; ++i) t10_insert(t, merged[i]);
      int n = 0;
      for (int i = 0; i < 10; ++i){
        if (t[i]){
          uint32_t pix = 0xFFFFFFFFu - (uint32_t)(t[i] & 0xFFFFFFFFull);
          s_bgr[n] = (int)(pix >> 8); s_bgc[n] = (int)(pix & 255u); ++n;
        }
      }
      s_nbg = n;
    }
    __syncthreads();
  }

  // ---- write dilated seed patches (<=180 pixels); duplicates write same value ----
  const int nfg = s_nfg, nbg = s_nbg;
  const int npts = nfg + nbg;
  if (tid < npts*9){
    int k = tid / 9, d = tid - k*9;
    int pr = (k < nfg) ? s_fgr[k] : s_bgr[k - nfg];
    int pc = (k < nfg) ? s_fgc[k] : s_bgc[k - nfg];
    pr += d/3 - 1; pc += d%3 - 1;
    if (pr >= 0 && pr < 256 && pc >= 0 && pc < 256){
      bool fgd = false, bgd = false;
      for (int i = 0; i < nfg; ++i) fgd |= (abs(pr - s_fgr[i]) <= 1) && (abs(pc - s_fgc[i]) <= 1);
      for (int i = 0; i < nbg; ++i) bgd |= (abs(pr - s_bgr[i]) <= 1) && (abs(pc - s_bgc[i]) <= 1);
      int val = (fgd && bgd) ? IGN : (fgd ? 1 : 0);
      outb[pr*256 + pc] = val;
    }
  }
}

extern "C" void kernel_launch(void* const* d_in, const int* in_sizes, int n_in,
                              void* d_out, int out_size, void* d_ws, size_t ws_size,
                              hipStream_t stream) {
  const float* x = (const float*)d_in[0];
  int* out = (int*)d_out;
  int B = in_sizes[0] / NPIX;
  apm_kernel<<<B, 256, 0, stream>>>(x, out);
}

// Round 3
// 177.607 us; speedup vs baseline: 2.3872x; 2.3872x over previous
//
#include <hip/hip_runtime.h>
#include <stdint.h>

#define NPIX 65536
#define IGN (-255)
#define CAP 768

// ---------------- threefry2x32 (exact JAX partitionable implementation) ----------------
__device__ __forceinline__ uint32_t rotl32(uint32_t v, uint32_t r){ return (v<<r)|(v>>(32u-r)); }

__device__ __forceinline__ void tf2x32(uint32_t k0, uint32_t k1, uint32_t x0, uint32_t x1,
                                       uint32_t &o0, uint32_t &o1){
  uint32_t k2 = k0 ^ k1 ^ 0x1BD11BDAu;
  x0 += k0; x1 += k1;
#define TFR(r) { x0 += x1; x1 = rotl32(x1,(r)); x1 ^= x0; }
  TFR(13u) TFR(15u) TFR(26u) TFR(6u)   x0 += k1; x1 += k2 + 1u;
  TFR(17u) TFR(29u) TFR(16u) TFR(24u)  x0 += k2; x1 += k0 + 2u;
  TFR(13u) TFR(15u) TFR(26u) TFR(6u)   x0 += k0; x1 += k1 + 3u;
  TFR(17u) TFR(29u) TFR(16u) TFR(24u)  x0 += k1; x1 += k2 + 4u;
  TFR(13u) TFR(15u) TFR(26u) TFR(6u)   x0 += k2; x1 += k0 + 5u;
#undef TFR
  o0 = x0; o1 = x1;
}

// pack score+index so that u64 max == (higher score, then lower index)
__device__ __forceinline__ unsigned long long packCand(uint32_t bits, uint32_t pix){
  float f = __uint_as_float((bits >> 9) | 0x3f800000u) - 1.0f;  // jax uniform [0,1)
  uint32_t u = __float_as_uint(f) ^ 0x80000000u;                // monotone map (f>=0)
  return ((unsigned long long)u << 32) | (unsigned long long)(0xFFFFFFFFu - pix);
}

// sorted-descending 10-element list, sentinel 0
__device__ __forceinline__ void t10_insert(unsigned long long* l, unsigned long long c){
  if (c > l[9]) {
    l[9] = c;
#pragma unroll
    for (int i = 9; i > 0; --i){
      unsigned long long a = l[i-1], b2 = l[i];
      if (b2 > a){ l[i-1] = b2; l[i] = a; }
    }
  }
}

__global__ __launch_bounds__(1024, 4)
void apm_kernel(const float* __restrict__ x, int* __restrict__ out){
  const int b = blockIdx.x;
  const int tid = threadIdx.x;
  const float* img = x + (size_t)b * NPIX;
  int* outb = out + (size_t)b * NPIX;

  __shared__ uint32_t hist[256];
  __shared__ float csum[256], cvsum[256];
  __shared__ unsigned long long buf[2][CAP];   // threshold-collected candidates (fg=0,bg=1)
  __shared__ uint32_t s_kw[4];
  __shared__ int s_cnt[2];
  __shared__ int s_nroi;
  __shared__ int s_imin;
  __shared__ unsigned long long s_best;
  __shared__ float s_lit;
  __shared__ int s_fail[2];
  __shared__ int s_pr[2][10], s_pc[2][10], s_np[2];

  if (tid < 256) hist[tid] = 0u;
  if (tid == 0){ s_cnt[0] = 0; s_cnt[1] = 0; s_nroi = 0; s_imin = 255; s_best = 0ull; }
  // partitionable split(key(1),(256,2)): key #m = threefry((0,1), 0, m) stacked (o0,o1)
  if (tid < 2){
    uint32_t o0, o1;
    tf2x32(0u, 1u, 0u, (uint32_t)(2*b + tid), o0, o1);
    s_kw[2*tid] = o0; s_kw[2*tid+1] = o1;
  }
  __syncthreads();

  // ---- pass 1: fill output with IGNORE, histogram, cache u8 in registers ----
  uint32_t packed[16];
  {
    int4 f4 = make_int4(IGN, IGN, IGN, IGN);
    const float4* x4 = (const float4*)img;
    int4* o4 = (int4*)outb;
#pragma unroll
    for (int j = 0; j < 16; ++j){
      int p4 = tid + 1024*j;
      float4 v = x4[p4];
      o4[p4] = f4;
      uint32_t u0 = (uint32_t)min(max((int)floorf(v.x*255.0f),0),255);
      uint32_t u1 = (uint32_t)min(max((int)floorf(v.y*255.0f),0),255);
      uint32_t u2 = (uint32_t)min(max((int)floorf(v.z*255.0f),0),255);
      uint32_t u3 = (uint32_t)min(max((int)floorf(v.w*255.0f),0),255);
      packed[j] = u0 | (u1<<8) | (u2<<16) | (u3<<24);
      atomicAdd(&hist[u0],1u); atomicAdd(&hist[u1],1u);
      atomicAdd(&hist[u2],1u); atomicAdd(&hist[u3],1u);
    }
  }
  __syncthreads();

  // ---- img_min ----
  if (tid < 256 && hist[tid]) atomicMin(&s_imin, tid);
  __syncthreads();
  const float img_min = (float)s_imin;

  // ---- parallel inclusive prefix scan of hist and hist*(i-img_min) ----
  // (all partial sums are exact integers < 2^24 -> any order is bit-exact vs jnp.cumsum)
  if (tid < 256){
    float h = (float)hist[tid];
    csum[tid]  = h;
    cvsum[tid] = h * ((float)tid - img_min);
  }
  __syncthreads();
  for (int off = 1; off < 256; off <<= 1){
    float a = 0.f, c2 = 0.f;
    if (tid < 256 && tid >= off){ a = csum[tid-off]; c2 = cvsum[tid-off]; }
    __syncthreads();
    if (tid < 256 && tid >= off){ csum[tid] += a; cvsum[tid] += c2; }
    __syncthreads();
  }

  // ---- Otsu: per-bin var_b + 64-bit argmax (first max wins) ----
  {
    float s_tot_o = cvsum[255] + img_min * csum[255];   // == sum(hist*i), exact int
    if (tid < 255){
      float w0 = csum[tid];
      float w1 = 65536.0f - w0;
      float cs = cvsum[tid] + img_min * csum[tid];      // == cumsum(hist*i)[tid], exact int
      float m0 = cs / fmaxf(w0, 1e-12f);
      float m1 = (s_tot_o - cs) / fmaxf(w1, 1e-12f);
      float d = m0 - m1;
      float vb = (w0*w1) * (d*d);
      unsigned long long pk =
        ((unsigned long long)__float_as_uint(vb) << 32) | (unsigned long long)(255 - tid);
      atomicMax(&s_best, pk);
    }
  }
  __syncthreads();

  // ---- Li iteration (serial, tiny) ----
  if (tid == 0){
    int bestIdx = 255 - (int)(s_best & 0xFFFFFFFFull);
    float otsu = fminf(fmaxf((float)bestIdx, 1.0f), 254.0f);
    float n_tot = csum[255], s_tot = cvsum[255];
    float t_curr = otsu - img_min, t_prev = t_curr + 10.0f;
    int it = 0;
    while (fabsf(t_curr - t_prev) > 0.5f && it < 64){
      int idx = min(max((int)floorf(t_curr + img_min), 0), 255);
      float n_back = csum[idx], s_back = cvsum[idx];
      float n_fore = n_tot - n_back, s_fore = s_tot - s_back;
      float mean_back = (n_back > 0.0f) ? (s_back / fmaxf(n_back, 1.0f)) : 0.0f;
      float mean_fore = s_fore / fmaxf(n_fore, 1.0f);
      float t_next = (mean_back - mean_fore) /
                     (logf(fmaxf(mean_back, 1e-12f)) - logf(fmaxf(mean_fore, 1e-12f)));
      if (mean_back < 1e-12f) t_next = mean_fore * 0.5f;
      t_prev = t_curr; t_curr = t_next; ++it;
    }
    s_lit = t_curr + img_min;
  }
  __syncthreads();

  // ---- scoring: threefry per pixel; collect scores in top 1/256 slice ----
  // mantissa-aligned cut: (bits>>9) >= 0x7F8000 <=> bits >= 0xFF000000; since the
  // score only depends on bits>>9, no tie can straddle the cut.
  const float lit = s_lit;
  const uint32_t fk0 = s_kw[0], fk1 = s_kw[1], bk0 = s_kw[2], bk1 = s_kw[3];
  const uint32_t THRM = (0xFF000000u >> 9);
  int my_roi = 0;
#pragma unroll
  for (int j = 0; j < 16; ++j){
    uint32_t pk = packed[j];
    uint32_t pix0 = (uint32_t)(4*(tid + 1024*j));
#pragma unroll
    for (int s = 0; s < 4; ++s){
      uint32_t q = (pk >> (8*s)) & 255u;
      bool r = ((float)q > lit);
      my_roi += r ? 1 : 0;
      uint32_t o0, o1;
      tf2x32(r ? fk0 : bk0, r ? fk1 : bk1, 0u, pix0 + (uint32_t)s, o0, o1);
      uint32_t bits = o0 ^ o1;
      if ((bits >> 9) >= THRM){
        int r2 = r ? 0 : 1;
        int idx = atomicAdd(&s_cnt[r2], 1);
        if (idx < CAP) buf[r2][idx] = packCand(bits, pix0 + (uint32_t)s);
      }
    }
  }
  for (int off = 32; off; off >>= 1) my_roi += __shfl_down(my_roi, off);
  if ((tid & 63) == 0) atomicAdd(&s_nroi, my_roi);
  __syncthreads();

  // ---- validity: need (collected >= 10) or (collected == region size); no overflow ----
  if (tid == 0){
    int m0r = s_nroi, m1r = NPIX - s_nroi;
    int c0 = s_cnt[0], c1 = s_cnt[1];
    s_fail[0] = (c0 > CAP) || (c0 < 10 && c0 != m0r);
    s_fail[1] = (c1 > CAP) || (c1 < 10 && c1 != m1r);
  }
  __syncthreads();

  // ---- fallback (statistically never runs; guarantees correctness) ----
  if (s_fail[0] || s_fail[1]){
    if (tid < 64){
      for (int r2 = 0; r2 < 2; ++r2){
        if (!s_fail[r2]) continue;
        uint32_t kk0 = s_kw[2*r2], kk1 = s_kw[2*r2+1];
        unsigned long long t[10];
#pragma unroll
        for (int i = 0; i < 10; ++i) t[i] = 0ull;
        for (int k2 = 0; k2 < 1024; ++k2){
          uint32_t pix = (uint32_t)(tid + 64*k2);
          float v = img[pix];
          int q = min(max((int)floorf(v*255.0f),0),255);
          bool r = ((float)q > lit);
          if (r != (r2 == 0)) continue;
          uint32_t o0, o1; tf2x32(kk0, kk1, 0u, pix, o0, o1);
          t10_insert(t, packCand(o0 ^ o1, pix));
        }
#pragma unroll
        for (int i = 0; i < 10; ++i) buf[r2][tid*10 + i] = t[i];
      }
    }
    __syncthreads();
    if (tid < 2 && s_fail[tid]){
      unsigned long long t[10];
#pragma unroll
      for (int i = 0; i < 10; ++i) t[i] = 0ull;
      for (int i = 0; i < 640; ++i) t10_insert(t, buf[tid][i]);
#pragma unroll
      for (int i = 0; i < 10; ++i) buf[tid][i] = t[i];
      s_cnt[tid] = 10;
    }
    __syncthreads();
  }

  // ---- extract top-10 points (fg on thread 0, bg on thread 64, parallel waves) ----
  if (tid == 0 || tid == 64){
    int r2 = (tid == 0) ? 0 : 1;
    int n = min(s_cnt[r2], CAP);
    unsigned long long t[10];
#pragma unroll
    for (int i = 0; i < 10; ++i) t[i] = 0ull;
    for (int i = 0; i < n; ++i) t10_insert(t, buf[r2][i]);
    int np = 0;
    for (int i = 0; i < 10; ++i){
      if (t[i]){
        uint32_t pix = 0xFFFFFFFFu - (uint32_t)(t[i] & 0xFFFFFFFFull);
        s_pr[r2][np] = (int)(pix >> 8);
        s_pc[r2][np] = (int)(pix & 255u);
        ++np;
      }
    }
    s_np[r2] = np;
  }
  __syncthreads();

  // ---- write dilated seed patches (<=180 px); duplicates write identical values ----
  const int nfg = s_np[0], nbg = s_np[1];
  const int npts = nfg + nbg;
  if (tid < npts*9){
    int k = tid / 9, d = tid - k*9;
    int pr = (k < nfg) ? s_pr[0][k] : s_pr[1][k - nfg];
    int pc = (k < nfg) ? s_pc[0][k] : s_pc[1][k - nfg];
    pr += d/3 - 1; pc += d%3 - 1;
    if (pr >= 0 && pr < 256 && pc >= 0 && pc < 256){
      bool fgd = false, bgd = false;
      for (int i = 0; i < nfg; ++i) fgd |= (abs(pr - s_pr[0][i]) <= 1) && (abs(pc - s_pc[0][i]) <= 1);
      for (int i = 0; i < nbg; ++i) bgd |= (abs(pr - s_pr[1][i]) <= 1) && (abs(pc - s_pc[1][i]) <= 1);
      int val = (fgd && bgd) ? IGN : (fgd ? 1 : 0);
      outb[pr*256 + pc] = val;
    }
  }
}

extern "C" void kernel_launch(void* const* d_in, const int* in_sizes, int n_in,
                              void* d_out, int out_size, void* d_ws, size_t ws_size,
                              hipStream_t stream) {
  const float* x = (const float*)d_in[0];
  int* out = (int*)d_out;
  int B = in_sizes[0] / NPIX;
  apm_kernel<<<B, 1024, 0, stream>>>(x, out);
}